// Round 2
// baseline (3344.239 us; speedup 1.0000x reference)
//
#include <hip/hip_runtime.h>

#define NB   16
#define NN   2048
#define NPTS (NB * NN)
#define KNB  6

// ---------------- squared-norm kernel ----------------
template<int C>
__global__ void sq_kernel(const float* __restrict__ x, float* __restrict__ sq) {
    int i = blockIdx.x * blockDim.x + threadIdx.x;
    if (i >= NPTS) return;
    const float4* r = (const float4*)(x + (size_t)i * C);
    float s = 0.f;
#pragma unroll
    for (int c = 0; c < C / 4; ++c) {
        float4 f = r[c];
        s += f.x * f.x + f.y * f.y + f.z * f.z + f.w * f.w;
    }
    sq[i] = s;
}

// ---------------- kNN scan kernel ----------------
// block = 256 thr = 4 waves. Wave w owns candidate group cg = blockIdx.z*4+w
// (128 candidates), and Q*64 queries (qg group). Each lane keeps Q private
// top-6 lists; at the end each wave writes packed u64 keys to plist[cg][q][k].
// key = sortable(d2_score) << 11 | cand_idx  -> min-order == (dist, idx) order.
template<int C, int Q, int TILE, int MINW>
__global__ __launch_bounds__(256, MINW)
void knn_scan(const float* __restrict__ x, const float* __restrict__ sq,
              unsigned long long* __restrict__ plist) {
    constexpr int QW = 64 * Q;   // queries per wave
    constexpr int CW = 128;      // candidates per wave (= one cg)

    __shared__ float tile[4][TILE * C];
    __shared__ float sqt[4][TILE];

    const int tid  = threadIdx.x;
    const int w    = tid >> 6;
    const int lane = tid & 63;
    const int qg   = blockIdx.x;
    const int b    = blockIdx.y;
    const int cg   = blockIdx.z * 4 + w;   // 0..15
    const int base = b * NN;
    const int cbase = cg * CW;             // batch-local candidate base

    // queries in registers
    float qreg[Q][C];
    int   qidx[Q];
#pragma unroll
    for (int qq = 0; qq < Q; ++qq) {
        qidx[qq] = qg * QW + qq * 64 + lane;   // batch-local
        const float* xp = x + (size_t)(base + qidx[qq]) * C;
#pragma unroll
        for (int c = 0; c < C; c += 4) {
            float4 f = *(const float4*)(xp + c);
            qreg[qq][c] = f.x; qreg[qq][c + 1] = f.y;
            qreg[qq][c + 2] = f.z; qreg[qq][c + 3] = f.w;
        }
    }

    float dl[Q][6];
    int   il[Q][6];
#pragma unroll
    for (int qq = 0; qq < Q; ++qq)
#pragma unroll
        for (int k = 0; k < 6; ++k) { dl[qq][k] = 1e30f; il[qq][k] = 0; }

    for (int t = 0; t < CW / TILE; ++t) {
        const int jb = cbase + t * TILE;
        // stage TILE candidates into this wave's private tile (no barrier:
        // wave-private LDS, compiler orders via lgkmcnt)
        {
            const float4* src = (const float4*)(x + (size_t)(base + jb) * C);
            float4* dst = (float4*)tile[w];
#pragma unroll
            for (int kk = 0; kk < (TILE * C) / 256; ++kk)
                dst[lane + 64 * kk] = src[lane + 64 * kk];
            if (lane < TILE) sqt[w][lane] = sq[base + jb + lane];
        }
        for (int jj = 0; jj < TILE; ++jj) {
            const float4* row = (const float4*)&tile[w][jj * C];
            float acc0[Q], acc1[Q];
#pragma unroll
            for (int qq = 0; qq < Q; ++qq) { acc0[qq] = 0.f; acc1[qq] = 0.f; }
#pragma unroll
            for (int c4 = 0; c4 < C / 4; ++c4) {
                float4 f = row[c4];
#pragma unroll
                for (int qq = 0; qq < Q; ++qq) {
                    acc0[qq] += f.x * qreg[qq][4 * c4]     + f.y * qreg[qq][4 * c4 + 1];
                    acc1[qq] += f.z * qreg[qq][4 * c4 + 2] + f.w * qreg[qq][4 * c4 + 3];
                }
            }
            const int j = jb + jj;
            const float sj = sqt[w][jj];
#pragma unroll
            for (int qq = 0; qq < Q; ++qq) {
                const float s = fmaf(-2.f, acc0[qq] + acc1[qq], sj);
                if (j != qidx[qq] && s < dl[qq][5]) {
                    dl[qq][5] = s; il[qq][5] = j;
#pragma unroll
                    for (int k = 4; k >= 0; --k) {
                        if (dl[qq][k + 1] < dl[qq][k]) {
                            float td = dl[qq][k]; dl[qq][k] = dl[qq][k + 1]; dl[qq][k + 1] = td;
                            int   ti = il[qq][k]; il[qq][k] = il[qq][k + 1]; il[qq][k + 1] = ti;
                        }
                    }
                }
            }
        }
    }

    // write packed partial lists (ascending within list)
#pragma unroll
    for (int qq = 0; qq < Q; ++qq) {
        unsigned long long* o = plist + ((size_t)cg * NPTS + (base + qidx[qq])) * KNB;
#pragma unroll
        for (int k = 0; k < 6; ++k) {
            unsigned u = __float_as_uint(dl[qq][k]);
            u ^= (u & 0x80000000u) ? 0xFFFFFFFFu : 0x80000000u;  // sortable
            o[k] = ((unsigned long long)u << 11) | (unsigned)(il[qq][k] & 2047);
        }
    }
}

// ---------------- kNN merge kernel ----------------
// thread = one query; merge 16 sorted 6-lists (u64 keys) -> top-6 indices.
__global__ __launch_bounds__(256) void knn_merge(const unsigned long long* __restrict__ plist,
                                                 int* __restrict__ nbr) {
    const int q = blockIdx.x * 256 + threadIdx.x;
    if (q >= NPTS) return;
    unsigned long long best[7];
#pragma unroll
    for (int k = 0; k < 6; ++k) best[k] = ~0ull;
    for (int cg = 0; cg < 16; ++cg) {
        const unsigned long long* p = plist + ((size_t)cg * NPTS + q) * KNB;
        for (int e = 0; e < 6; ++e) {
            unsigned long long v = p[e];
            if (v >= best[5]) break;   // sublist ascending -> rest are larger
            best[5] = v;
#pragma unroll
            for (int k = 4; k >= 0; --k) {
                if (best[k + 1] < best[k]) {
                    unsigned long long t = best[k]; best[k] = best[k + 1]; best[k + 1] = t;
                }
            }
        }
    }
    const int b = q >> 11;
#pragma unroll
    for (int k = 0; k < 6; ++k)
        nbr[q * KNB + k] = (b << 11) | (int)(best[k] & 2047ull);
}

// ---------------- edge MLP kernel ----------------
template<int CIN, int COUT, bool RESID>
__global__ __launch_bounds__(64) void mlp_kernel(const float* __restrict__ xin,
                                                 const int* __restrict__ nbr,
                                                 const float* __restrict__ W1,
                                                 const float* __restrict__ b1,
                                                 const float* __restrict__ W2,
                                                 const float* __restrict__ b2,
                                                 const float* __restrict__ resid,
                                                 float* __restrict__ out) {
    const int lane = threadIdx.x;
    const int o = lane & (COUT - 1);

    float w1c[2 * CIN];
    float w2c[COUT];
#pragma unroll
    for (int c = 0; c < 2 * CIN; ++c) w1c[c] = W1[c * COUT + o];
#pragma unroll
    for (int c = 0; c < COUT; ++c) w2c[c] = W2[c * COUT + o];
    const float b1v = b1[o];
    const float b2v = b2[o];

    __shared__ __align__(16) float msg[2 * CIN];
    __shared__ __align__(16) float h1[COUT];

    for (int i = blockIdx.x; i < NPTS; i += gridDim.x) {
        float xiv = 0.f;
        if (lane < CIN) {
            xiv = xin[(size_t)i * CIN + lane];
            msg[lane] = xiv;
        }
        float best = -1e38f;
        for (int n = 0; n < KNB; ++n) {
            const int j = nbr[i * KNB + n];
            if (lane < CIN) msg[CIN + lane] = xin[(size_t)j * CIN + lane] - xiv;
            __syncthreads();
            float acc0 = b1v, acc1 = 0.f;
#pragma unroll
            for (int c4 = 0; c4 < (2 * CIN) / 4; ++c4) {
                float4 f = ((const float4*)msg)[c4];
                acc0 += f.x * w1c[4 * c4]     + f.y * w1c[4 * c4 + 1];
                acc1 += f.z * w1c[4 * c4 + 2] + f.w * w1c[4 * c4 + 3];
            }
            const float h = fmaxf(acc0 + acc1, 0.f);
            __syncthreads();
            if (lane < COUT) h1[lane] = h;
            __syncthreads();
            float a0 = b2v, a1 = 0.f;
#pragma unroll
            for (int c4 = 0; c4 < COUT / 4; ++c4) {
                float4 f = ((const float4*)h1)[c4];
                a0 += f.x * w2c[4 * c4]     + f.y * w2c[4 * c4 + 1];
                a1 += f.z * w2c[4 * c4 + 2] + f.w * w2c[4 * c4 + 3];
            }
            best = fmaxf(best, a0 + a1);
            __syncthreads();
        }
        if (lane < COUT) {
            float v = best;
            if (RESID) v += resid[(size_t)i * 64 + lane];
            v = fmaxf(v, 0.f);
            out[(size_t)i * COUT + lane] = v;
        }
    }
}

extern "C" void kernel_launch(void* const* d_in, const int* in_sizes, int n_in,
                              void* d_out, int out_size, void* d_ws, size_t ws_size,
                              hipStream_t stream) {
    const float* x    = (const float*)d_in[0];
    const float* W1_0 = (const float*)d_in[2];
    const float* b1_0 = (const float*)d_in[3];
    const float* W2_0 = (const float*)d_in[4];
    const float* b2_0 = (const float*)d_in[5];
    const float* W1_1 = (const float*)d_in[6];
    const float* b1_1 = (const float*)d_in[7];
    const float* W2_1 = (const float*)d_in[8];
    const float* b2_1 = (const float*)d_in[9];
    const float* W1_2 = (const float*)d_in[10];
    const float* b1_2 = (const float*)d_in[11];
    const float* W2_2 = (const float*)d_in[12];
    const float* b2_2 = (const float*)d_in[13];
    float* outp = (float*)d_out;

    // workspace layout
    float* x0  = (float*)d_ws;                   // 32768 x 64
    float* x1  = x0 + (size_t)NPTS * 64;         // 32768 x 32
    float* sqb = x1 + (size_t)NPTS * 32;         // 32768
    int*   nbr = (int*)(sqb + NPTS);             // 32768 x 6
    unsigned long long* plist = (unsigned long long*)(nbr + (size_t)NPTS * KNB); // 16*32768*6

    const dim3 g32(8, NB, 4);    // C=32, Q=4: 8 qgroups of 256 queries
    const dim3 g64(16, NB, 4);   // C=64, Q=2: 16 qgroups of 128 queries
    const int  mgrid = NPTS / 256;

    // ---- layer 0: x (32) -> x0 (64), relu ----
    sq_kernel<32><<<NPTS / 256, 256, 0, stream>>>(x, sqb);
    knn_scan<32, 4, 64, 2><<<g32, 256, 0, stream>>>(x, sqb, plist);
    knn_merge<<<mgrid, 256, 0, stream>>>(plist, nbr);
    mlp_kernel<32, 64, false><<<2048, 64, 0, stream>>>(x, nbr, W1_0, b1_0, W2_0, b2_0, nullptr, x0);

    // ---- layer 1: x0 (64) -> x1 (32), relu ----
    sq_kernel<64><<<NPTS / 256, 256, 0, stream>>>(x0, sqb);
    knn_scan<64, 2, 32, 3><<<g64, 256, 0, stream>>>(x0, sqb, plist);
    knn_merge<<<mgrid, 256, 0, stream>>>(plist, nbr);
    mlp_kernel<64, 32, false><<<2048, 64, 0, stream>>>(x0, nbr, W1_1, b1_1, W2_1, b2_1, nullptr, x1);

    // ---- layer 2: x1 (32) -> out (64), +x0 residual, relu ----
    sq_kernel<32><<<NPTS / 256, 256, 0, stream>>>(x1, sqb);
    knn_scan<32, 4, 64, 2><<<g32, 256, 0, stream>>>(x1, sqb, plist);
    knn_merge<<<mgrid, 256, 0, stream>>>(plist, nbr);
    mlp_kernel<32, 64, true><<<2048, 64, 0, stream>>>(x1, nbr, W1_2, b1_2, W2_2, b2_2, x0, outp);
}

// Round 3
// 994.510 us; speedup vs baseline: 3.3627x; 3.3627x over previous
//
#include <hip/hip_runtime.h>

#define NB   16
#define NN   2048
#define NPTS (NB * NN)
#define KNB  6
#define SPLIT 8          // candidate groups per batch (partial top-6 lists)

// ---------------- squared-norm kernel ----------------
template<int C>
__global__ void sq_kernel(const float* __restrict__ x, float* __restrict__ sq) {
    int i = blockIdx.x * blockDim.x + threadIdx.x;
    if (i >= NPTS) return;
    const float4* r = (const float4*)(x + (size_t)i * C);
    float s = 0.f;
#pragma unroll
    for (int c = 0; c < C / 4; ++c) {
        float4 f = r[c];
        s += f.x * f.x + f.y * f.y + f.z * f.z + f.w * f.w;
    }
    sq[i] = s;
}

// ---------------- weight prep: transpose the three W1s ----------------
// W1 stored [2*CIN][COUT] row-major; we need rows of W1^T = [COUT][2*CIN]
// so the MLP can stream a contiguous per-output-channel row via scalar loads.
__global__ void prep_w(const float* __restrict__ W10, const float* __restrict__ W11,
                       const float* __restrict__ W12,
                       float* __restrict__ T0, float* __restrict__ T1,
                       float* __restrict__ T2) {
    int t = blockIdx.x * 256 + threadIdx.x;
    if (t < 4096) { int o = t >> 6, c = t & 63;  T0[o * 64 + c]  = W10[c * 64 + o]; }
    if (t < 4096) { int o = t >> 7, c = t & 127; T1[o * 128 + c] = W11[c * 32 + o]; }
    if (t < 4096) { int o = t >> 6, c = t & 63;  T2[o * 64 + c]  = W12[c * 64 + o]; }
}

// ---------------- kNN scan kernel ----------------
// block = 256 thr = 4 waves. lane = query (Q=1, 64 queries/wave).
// Wave w scans candidate group cg = blockIdx.z*4+w (NN/SPLIT candidates).
// Candidate rows are wave-uniform -> scalar (s_load) broadcast, zero LDS.
// Each lane keeps a private top-6; writes packed sortable u64 keys to plist.
template<int C, int MINW>
__global__ __launch_bounds__(256, MINW)
void knn_scan(const float* __restrict__ x, const float* __restrict__ sq,
              unsigned long long* __restrict__ plist) {
    const int lane = threadIdx.x & 63;
    const int w    = __builtin_amdgcn_readfirstlane(threadIdx.x >> 6);
    const int b    = blockIdx.y;
    const int base = b * NN;
    const int q    = blockIdx.x * 64 + lane;      // batch-local query index
    const int cg   = blockIdx.z * 4 + w;          // 0..SPLIT-1
    const int cbase = cg * (NN / SPLIT);

    // query features in registers (per-lane vector loads)
    float qreg[C];
    {
        const float* qp = x + (size_t)(base + q) * C;
#pragma unroll
        for (int c = 0; c < C; c += 4) {
            float4 f = *(const float4*)(qp + c);
            qreg[c] = f.x; qreg[c + 1] = f.y; qreg[c + 2] = f.z; qreg[c + 3] = f.w;
        }
    }

    float dl[6]; int il[6];
#pragma unroll
    for (int k = 0; k < 6; ++k) { dl[k] = 1e30f; il[k] = 0; }

    for (int j = 0; j < NN / SPLIT; ++j) {
        const int jg = cbase + j;                  // batch-local candidate
        const float* rp = x + (size_t)(base + jg) * C;  // wave-uniform address
        float a0 = 0.f, a1 = 0.f, a2 = 0.f, a3 = 0.f;
#pragma unroll
        for (int c = 0; c < C; c += 4) {
            a0 = fmaf(rp[c],     qreg[c],     a0);
            a1 = fmaf(rp[c + 1], qreg[c + 1], a1);
            a2 = fmaf(rp[c + 2], qreg[c + 2], a2);
            a3 = fmaf(rp[c + 3], qreg[c + 3], a3);
        }
        const float s = fmaf(-2.f, (a0 + a1) + (a2 + a3), sq[base + jg]);
        if (jg != q && s < dl[5]) {
            dl[5] = s; il[5] = jg;
#pragma unroll
            for (int k = 4; k >= 0; --k) {
                if (dl[k + 1] < dl[k]) {
                    float td = dl[k]; dl[k] = dl[k + 1]; dl[k + 1] = td;
                    int   ti = il[k]; il[k] = il[k + 1]; il[k + 1] = ti;
                }
            }
        }
    }

    // packed sortable keys: (flip(score) << 11) | cand_idx  (ascending order)
    unsigned long long* o = plist + ((size_t)cg * NPTS + (base + q)) * KNB;
#pragma unroll
    for (int k = 0; k < 6; ++k) {
        unsigned u = __float_as_uint(dl[k]);
        u ^= (u & 0x80000000u) ? 0xFFFFFFFFu : 0x80000000u;
        o[k] = ((unsigned long long)u << 11) | (unsigned)(il[k] & 2047);
    }
}

// ---------------- kNN merge kernel ----------------
// thread = one query; merge SPLIT sorted 6-lists -> top-6 global indices.
__global__ __launch_bounds__(256) void knn_merge(const unsigned long long* __restrict__ plist,
                                                 int* __restrict__ nbr) {
    const int q = blockIdx.x * 256 + threadIdx.x;
    if (q >= NPTS) return;
    unsigned long long best[6];
#pragma unroll
    for (int k = 0; k < 6; ++k) best[k] = ~0ull;
    for (int cg = 0; cg < SPLIT; ++cg) {
        const unsigned long long* p = plist + ((size_t)cg * NPTS + q) * KNB;
        for (int e = 0; e < 6; ++e) {
            unsigned long long v = p[e];
            if (v >= best[5]) break;   // sublist ascending
            best[5] = v;
#pragma unroll
            for (int k = 4; k >= 0; --k) {
                if (best[k + 1] < best[k]) {
                    unsigned long long t = best[k]; best[k] = best[k + 1]; best[k + 1] = t;
                }
            }
        }
    }
    const int b = q >> 11;
#pragma unroll
    for (int k = 0; k < 6; ++k)
        nbr[q * KNB + k] = (b << 11) | (int)(best[k] & 2047ull);
}

// ---------------- edge MLP kernel (transpose formulation) ----------------
// block = 384 thr = 6 waves; lane = point (64 points/block); wave = neighbor.
// All weight/bias loads are wave-uniform (scalar broadcast, zero LDS in the
// hot loop). Final 6-way max combined via a 3-barrier LDS tree.
// u[o] = sum_{o'} W2[o'][o] * relu(b1[o'] + W1T[o'][:] . msg)  (b2 folded at store)
template<int CIN, int COUT, bool RESID, int MINW>
__global__ __launch_bounds__(384, MINW)
void mlp_kernel(const float* __restrict__ xin, const int* __restrict__ nbr,
                const float* __restrict__ W1T, const float* __restrict__ b1,
                const float* __restrict__ W2,  const float* __restrict__ b2,
                const float* __restrict__ resid, float* __restrict__ out) {
    constexpr int RS = COUT + 4;        // padded row (16B-aligned stride)
    __shared__ float Buf[3][64][RS];

    const int lane = threadIdx.x & 63;
    const int w    = __builtin_amdgcn_readfirstlane(threadIdx.x >> 6);  // 0..5
    const int i    = blockIdx.x * 64 + lane;

    // xi and xd = xj - xi in registers (per-lane loads)
    float xi[CIN], xd[CIN];
    {
        const float* xp = xin + (size_t)i * CIN;
#pragma unroll
        for (int c = 0; c < CIN; c += 4) {
            float4 f = *(const float4*)(xp + c);
            xi[c] = f.x; xi[c + 1] = f.y; xi[c + 2] = f.z; xi[c + 3] = f.w;
        }
        const int j = nbr[i * KNB + w];
        const float* jp = xin + (size_t)j * CIN;
#pragma unroll
        for (int c = 0; c < CIN; c += 4) {
            float4 f = *(const float4*)(jp + c);
            xd[c]     = f.x - xi[c];     xd[c + 1] = f.y - xi[c + 1];
            xd[c + 2] = f.z - xi[c + 2]; xd[c + 3] = f.w - xi[c + 3];
        }
    }

    float uacc[COUT];
#pragma unroll
    for (int o = 0; o < COUT; ++o) uacc[o] = 0.f;

    for (int op = 0; op < COUT; ++op) {
        const float* w1r = W1T + (size_t)op * (2 * CIN);   // wave-uniform row
        float h0 = 0.f, h1 = 0.f, h2 = 0.f, h3 = 0.f;
#pragma unroll
        for (int c = 0; c < CIN; c += 4) {
            h0 = fmaf(w1r[c],     xi[c],     h0);
            h1 = fmaf(w1r[c + 1], xi[c + 1], h1);
            h2 = fmaf(w1r[c + 2], xi[c + 2], h2);
            h3 = fmaf(w1r[c + 3], xi[c + 3], h3);
        }
#pragma unroll
        for (int c = 0; c < CIN; c += 4) {
            h0 = fmaf(w1r[CIN + c],     xd[c],     h0);
            h1 = fmaf(w1r[CIN + c + 1], xd[c + 1], h1);
            h2 = fmaf(w1r[CIN + c + 2], xd[c + 2], h2);
            h3 = fmaf(w1r[CIN + c + 3], xd[c + 3], h3);
        }
        const float h = fmaxf((h0 + h1) + (h2 + h3) + b1[op], 0.f);
        const float* w2r = W2 + (size_t)op * COUT;          // contiguous row
#pragma unroll
        for (int o = 0; o < COUT; ++o)
            uacc[o] = fmaf(w2r[o], h, uacc[o]);
    }

    // 6 -> 1 max reduction: waves {3,4,5} -> Buf{0,1,2}; waves {0,1,2} fold;
    // waves {1,2} republish; wave 0 finalizes.
    if (w >= 3) {
#pragma unroll
        for (int o = 0; o < COUT; ++o) Buf[w - 3][lane][o] = uacc[o];
    }
    __syncthreads();
    if (w < 3) {
#pragma unroll
        for (int o = 0; o < COUT; ++o) uacc[o] = fmaxf(uacc[o], Buf[w][lane][o]);
    }
    __syncthreads();
    if (w == 1 || w == 2) {
#pragma unroll
        for (int o = 0; o < COUT; ++o) Buf[w][lane][o] = uacc[o];
    }
    __syncthreads();
    if (w == 0) {
        float* po = out + (size_t)i * COUT;
#pragma unroll
        for (int o = 0; o < COUT; ++o) {
            float v = fmaxf(uacc[o], fmaxf(Buf[1][lane][o], Buf[2][lane][o])) + b2[o];
            if (RESID) v += resid[(size_t)i * COUT + o];
            po[o] = fmaxf(v, 0.f);
        }
    }
}

extern "C" void kernel_launch(void* const* d_in, const int* in_sizes, int n_in,
                              void* d_out, int out_size, void* d_ws, size_t ws_size,
                              hipStream_t stream) {
    const float* x    = (const float*)d_in[0];
    const float* W1_0 = (const float*)d_in[2];
    const float* b1_0 = (const float*)d_in[3];
    const float* W2_0 = (const float*)d_in[4];
    const float* b2_0 = (const float*)d_in[5];
    const float* W1_1 = (const float*)d_in[6];
    const float* b1_1 = (const float*)d_in[7];
    const float* W2_1 = (const float*)d_in[8];
    const float* b2_1 = (const float*)d_in[9];
    const float* W1_2 = (const float*)d_in[10];
    const float* b1_2 = (const float*)d_in[11];
    const float* W2_2 = (const float*)d_in[12];
    const float* b2_2 = (const float*)d_in[13];
    float* outp = (float*)d_out;

    // workspace layout (plist first for 8B alignment)
    unsigned long long* plist = (unsigned long long*)d_ws;        // SPLIT*NPTS*6
    float* x0  = (float*)(plist + (size_t)SPLIT * NPTS * KNB);    // 32768 x 64
    float* x1  = x0 + (size_t)NPTS * 64;                          // 32768 x 32
    float* sqb = x1 + (size_t)NPTS * 32;                          // 32768
    float* T0  = sqb + NPTS;                                      // 64 x 64
    float* T1  = T0 + 4096;                                       // 32 x 128
    float* T2  = T1 + 4096;                                       // 64 x 64
    int*   nbr = (int*)(T2 + 4096);                               // 32768 x 6

    const dim3 gscan(NN / 64, NB, SPLIT / 4);   // (32,16,2) x 256thr = 4096 waves
    const int  mgrid = NPTS / 256;
    const int  pgrid = NPTS / 64;               // 512 blocks x 6 waves

    prep_w<<<16, 256, 0, stream>>>(W1_0, W1_1, W1_2, T0, T1, T2);

    // ---- layer 0: x (32) -> x0 (64), relu ----
    sq_kernel<32><<<NPTS / 256, 256, 0, stream>>>(x, sqb);
    knn_scan<32, 4><<<gscan, 256, 0, stream>>>(x, sqb, plist);
    knn_merge<<<mgrid, 256, 0, stream>>>(plist, nbr);
    mlp_kernel<32, 64, false, 3><<<pgrid, 384, 0, stream>>>(x, nbr, T0, b1_0, W2_0, b2_0, nullptr, x0);

    // ---- layer 1: x0 (64) -> x1 (32), relu ----
    sq_kernel<64><<<NPTS / 256, 256, 0, stream>>>(x0, sqb);
    knn_scan<64, 3><<<gscan, 256, 0, stream>>>(x0, sqb, plist);
    knn_merge<<<mgrid, 256, 0, stream>>>(plist, nbr);
    mlp_kernel<64, 32, false, 2><<<pgrid, 384, 0, stream>>>(x0, nbr, T1, b1_1, W2_1, b2_1, nullptr, x1);

    // ---- layer 2: x1 (32) -> out (64), +x0 residual, relu ----
    sq_kernel<32><<<NPTS / 256, 256, 0, stream>>>(x1, sqb);
    knn_scan<32, 4><<<gscan, 256, 0, stream>>>(x1, sqb, plist);
    knn_merge<<<mgrid, 256, 0, stream>>>(plist, nbr);
    mlp_kernel<32, 64, true, 3><<<pgrid, 384, 0, stream>>>(x1, nbr, T2, b1_2, W2_2, b2_2, x0, outp);
}

// Round 4
// 938.212 us; speedup vs baseline: 3.5645x; 1.0600x over previous
//
#include <hip/hip_runtime.h>

#define NB   16
#define NN   2048
#define NPTS (NB * NN)
#define KNB  6
#define SPLIT 8          // candidate ranges per batch (partial top-6 lists)

typedef const __attribute__((address_space(1))) void* gas_p;
typedef __attribute__((address_space(3))) void* las_p;

// ---------------- squared-norm kernel ----------------
template<int C>
__global__ void sq_kernel(const float* __restrict__ x, float* __restrict__ sq) {
    int i = blockIdx.x * blockDim.x + threadIdx.x;
    if (i >= NPTS) return;
    const float4* r = (const float4*)(x + (size_t)i * C);
    float s = 0.f;
#pragma unroll
    for (int c = 0; c < C / 4; ++c) {
        float4 f = r[c];
        s += f.x * f.x + f.y * f.y + f.z * f.z + f.w * f.w;
    }
    sq[i] = s;
}

// ---------------- weight prep: transpose the three W1s ----------------
__global__ void prep_w(const float* __restrict__ W10, const float* __restrict__ W11,
                       const float* __restrict__ W12,
                       float* __restrict__ T0, float* __restrict__ T1,
                       float* __restrict__ T2) {
    int t = blockIdx.x * 256 + threadIdx.x;
    if (t < 4096) { int o = t >> 6, c = t & 63;  T0[o * 64 + c]  = W10[c * 64 + o]; }
    if (t < 4096) { int o = t >> 7, c = t & 127; T1[o * 128 + c] = W11[c * 32 + o]; }
    if (t < 4096) { int o = t >> 6, c = t & 63;  T2[o * 64 + c]  = W12[c * 64 + o]; }
}

// branchless stable insert of (s, j) into ascending 6-list
__device__ __forceinline__ void insert6(float s, int j, float* dl, int* il) {
    float cd = s; int ci = j;
#pragma unroll
    for (int k = 0; k < 6; ++k) {
        const float od = dl[k]; const int oi = il[k];
        const bool c = cd < od;          // strict: existing wins ties -> stable
        dl[k] = c ? cd : od;
        il[k] = c ? ci : oi;
        cd = c ? od : cd;
        ci = c ? oi : ci;
    }
}

// ---------------- kNN scan kernel ----------------
// block = 256 thr = 4 waves, grid (NN/512, NB, SPLIT).
// Block scans candidate range [z*256, z*256+256) for 512 queries
// (wave w: queries qg*512 + w*128 + {lane, lane+64}; Q=2 per lane).
// Candidates staged to one shared LDS tile via global_load_lds (width 16),
// consumed as broadcast ds_read_b128. Branchless top-6 insertion.
template<int C, int MINW>
__global__ __launch_bounds__(256, MINW)
void knn_scan(const float* __restrict__ x, const float* __restrict__ sq,
              unsigned long long* __restrict__ plist) {
    constexpr int TILE = 64;
    constexpr int RANGE = NN / SPLIT;       // 256
    constexpr int CH = TILE * C / 256;      // 1KB staging chunks per tile
    __shared__ float tile[TILE * C];
    __shared__ float sqt[TILE];

    const int tid  = threadIdx.x;
    const int w    = tid >> 6;
    const int lane = tid & 63;
    const int b    = blockIdx.y;
    const int z    = blockIdx.z;            // 0..SPLIT-1
    const int base = b * NN;
    const int q0   = blockIdx.x * 512 + w * 128 + lane;   // batch-local
    const int q1   = q0 + 64;
    const int cbase = z * RANGE;

    // two queries per lane, in registers
    float q0r[C], q1r[C];
    {
        const float* p0 = x + (size_t)(base + q0) * C;
        const float* p1 = x + (size_t)(base + q1) * C;
#pragma unroll
        for (int c = 0; c < C; c += 4) {
            float4 f = *(const float4*)(p0 + c);
            q0r[c] = f.x; q0r[c + 1] = f.y; q0r[c + 2] = f.z; q0r[c + 3] = f.w;
            float4 h = *(const float4*)(p1 + c);
            q1r[c] = h.x; q1r[c + 1] = h.y; q1r[c + 2] = h.z; q1r[c + 3] = h.w;
        }
    }

    float dl0[6], dl1[6]; int il0[6], il1[6];
#pragma unroll
    for (int k = 0; k < 6; ++k) { dl0[k] = 1e30f; dl1[k] = 1e30f; il0[k] = 0; il1[k] = 0; }

    for (int t = 0; t < RANGE / TILE; ++t) {
        const int jb = cbase + t * TILE;
        // ---- stage TILE candidate rows + their sq into LDS (async, no VGPR round-trip)
        {
            const float* gsrc = x + (size_t)(base + jb) * C;
#pragma unroll
            for (int k = w; k < CH; k += 4)
                __builtin_amdgcn_global_load_lds(
                    (gas_p)(gsrc + k * 256 + lane * 4),
                    (las_p)(tile + k * 256), 16, 0, 0);
            if (w == 0)
                __builtin_amdgcn_global_load_lds(
                    (gas_p)(sq + base + jb + lane),
                    (las_p)sqt, 4, 0, 0);
        }
        __syncthreads();
        // ---- scan the tile
        for (int jj = 0; jj < TILE; ++jj) {
            const float4* row = (const float4*)(tile + jj * C);
            float a0 = 0.f, a1 = 0.f, a2 = 0.f, a3 = 0.f;
            float b0 = 0.f, b1v = 0.f, b2v = 0.f, b3 = 0.f;
#pragma unroll
            for (int c4 = 0; c4 < C / 4; ++c4) {
                float4 f = row[c4];
                a0 = fmaf(f.x, q0r[4 * c4],     a0);
                a1 = fmaf(f.y, q0r[4 * c4 + 1], a1);
                a2 = fmaf(f.z, q0r[4 * c4 + 2], a2);
                a3 = fmaf(f.w, q0r[4 * c4 + 3], a3);
                b0  = fmaf(f.x, q1r[4 * c4],     b0);
                b1v = fmaf(f.y, q1r[4 * c4 + 1], b1v);
                b2v = fmaf(f.z, q1r[4 * c4 + 2], b2v);
                b3  = fmaf(f.w, q1r[4 * c4 + 3], b3);
            }
            const int j = jb + jj;
            const float sj = sqt[jj];
            float s0 = fmaf(-2.f, (a0 + a1) + (a2 + a3), sj);
            float s1 = fmaf(-2.f, (b0 + b1v) + (b2v + b3), sj);
            s0 = (j == q0) ? 1e30f : s0;
            s1 = (j == q1) ? 1e30f : s1;
            insert6(s0, j, dl0, il0);
            insert6(s1, j, dl1, il1);
        }
        __syncthreads();
    }

    // packed sortable keys: (flip(score) << 11) | cand_idx (ascending)
    {
        unsigned long long* o = plist + ((size_t)z * NPTS + (base + q0)) * KNB;
#pragma unroll
        for (int k = 0; k < 6; ++k) {
            unsigned u = __float_as_uint(dl0[k]);
            u ^= (u & 0x80000000u) ? 0xFFFFFFFFu : 0x80000000u;
            o[k] = ((unsigned long long)u << 11) | (unsigned)(il0[k] & 2047);
        }
        unsigned long long* o1 = plist + ((size_t)z * NPTS + (base + q1)) * KNB;
#pragma unroll
        for (int k = 0; k < 6; ++k) {
            unsigned u = __float_as_uint(dl1[k]);
            u ^= (u & 0x80000000u) ? 0xFFFFFFFFu : 0x80000000u;
            o1[k] = ((unsigned long long)u << 11) | (unsigned)(il1[k] & 2047);
        }
    }
}

// ---------------- kNN merge kernel ----------------
__global__ __launch_bounds__(256) void knn_merge(const unsigned long long* __restrict__ plist,
                                                 int* __restrict__ nbr) {
    const int q = blockIdx.x * 256 + threadIdx.x;
    if (q >= NPTS) return;
    unsigned long long best[6];
#pragma unroll
    for (int k = 0; k < 6; ++k) best[k] = ~0ull;
    for (int cg = 0; cg < SPLIT; ++cg) {
        const unsigned long long* p = plist + ((size_t)cg * NPTS + q) * KNB;
        for (int e = 0; e < 6; ++e) {
            unsigned long long v = p[e];
            if (v >= best[5]) break;   // sublist ascending
            best[5] = v;
#pragma unroll
            for (int k = 4; k >= 0; --k) {
                if (best[k + 1] < best[k]) {
                    unsigned long long t = best[k]; best[k] = best[k + 1]; best[k + 1] = t;
                }
            }
        }
    }
    const int b = q >> 11;
#pragma unroll
    for (int k = 0; k < 6; ++k)
        nbr[q * KNB + k] = (b << 11) | (int)(best[k] & 2047ull);
}

// ---------------- edge MLP kernel (transpose formulation) ----------------
// block = 384 thr = 6 waves; lane = point; wave = neighbor. Weight loads are
// wave-uniform scalar broadcasts; 6->1 max via 3-barrier LDS tree.
template<int CIN, int COUT, bool RESID, int MINW>
__global__ __launch_bounds__(384, MINW)
void mlp_kernel(const float* __restrict__ xin, const int* __restrict__ nbr,
                const float* __restrict__ W1T, const float* __restrict__ b1,
                const float* __restrict__ W2,  const float* __restrict__ b2,
                const float* __restrict__ resid, float* __restrict__ out) {
    constexpr int RS = COUT + 4;
    __shared__ float Buf[3][64][RS];

    const int lane = threadIdx.x & 63;
    const int w    = __builtin_amdgcn_readfirstlane(threadIdx.x >> 6);  // 0..5
    const int i    = blockIdx.x * 64 + lane;

    float xi[CIN], xd[CIN];
    {
        const float* xp = xin + (size_t)i * CIN;
#pragma unroll
        for (int c = 0; c < CIN; c += 4) {
            float4 f = *(const float4*)(xp + c);
            xi[c] = f.x; xi[c + 1] = f.y; xi[c + 2] = f.z; xi[c + 3] = f.w;
        }
        const int j = nbr[i * KNB + w];
        const float* jp = xin + (size_t)j * CIN;
#pragma unroll
        for (int c = 0; c < CIN; c += 4) {
            float4 f = *(const float4*)(jp + c);
            xd[c]     = f.x - xi[c];     xd[c + 1] = f.y - xi[c + 1];
            xd[c + 2] = f.z - xi[c + 2]; xd[c + 3] = f.w - xi[c + 3];
        }
    }

    float uacc[COUT];
#pragma unroll
    for (int o = 0; o < COUT; ++o) uacc[o] = 0.f;

    for (int op = 0; op < COUT; ++op) {
        const float* w1r = W1T + (size_t)op * (2 * CIN);
        float h0 = 0.f, h1 = 0.f, h2 = 0.f, h3 = 0.f;
#pragma unroll
        for (int c = 0; c < CIN; c += 4) {
            h0 = fmaf(w1r[c],     xi[c],     h0);
            h1 = fmaf(w1r[c + 1], xi[c + 1], h1);
            h2 = fmaf(w1r[c + 2], xi[c + 2], h2);
            h3 = fmaf(w1r[c + 3], xi[c + 3], h3);
        }
#pragma unroll
        for (int c = 0; c < CIN; c += 4) {
            h0 = fmaf(w1r[CIN + c],     xd[c],     h0);
            h1 = fmaf(w1r[CIN + c + 1], xd[c + 1], h1);
            h2 = fmaf(w1r[CIN + c + 2], xd[c + 2], h2);
            h3 = fmaf(w1r[CIN + c + 3], xd[c + 3], h3);
        }
        const float h = fmaxf((h0 + h1) + (h2 + h3) + b1[op], 0.f);
        const float* w2r = W2 + (size_t)op * COUT;
#pragma unroll
        for (int o = 0; o < COUT; ++o)
            uacc[o] = fmaf(w2r[o], h, uacc[o]);
    }

    if (w >= 3) {
#pragma unroll
        for (int o = 0; o < COUT; ++o) Buf[w - 3][lane][o] = uacc[o];
    }
    __syncthreads();
    if (w < 3) {
#pragma unroll
        for (int o = 0; o < COUT; ++o) uacc[o] = fmaxf(uacc[o], Buf[w][lane][o]);
    }
    __syncthreads();
    if (w == 1 || w == 2) {
#pragma unroll
        for (int o = 0; o < COUT; ++o) Buf[w][lane][o] = uacc[o];
    }
    __syncthreads();
    if (w == 0) {
        float* po = out + (size_t)i * COUT;
#pragma unroll
        for (int o = 0; o < COUT; ++o) {
            float v = fmaxf(uacc[o], fmaxf(Buf[1][lane][o], Buf[2][lane][o])) + b2[o];
            if (RESID) v += resid[(size_t)i * COUT + o];
            po[o] = fmaxf(v, 0.f);
        }
    }
}

extern "C" void kernel_launch(void* const* d_in, const int* in_sizes, int n_in,
                              void* d_out, int out_size, void* d_ws, size_t ws_size,
                              hipStream_t stream) {
    const float* x    = (const float*)d_in[0];
    const float* W1_0 = (const float*)d_in[2];
    const float* b1_0 = (const float*)d_in[3];
    const float* W2_0 = (const float*)d_in[4];
    const float* b2_0 = (const float*)d_in[5];
    const float* W1_1 = (const float*)d_in[6];
    const float* b1_1 = (const float*)d_in[7];
    const float* W2_1 = (const float*)d_in[8];
    const float* b2_1 = (const float*)d_in[9];
    const float* W1_2 = (const float*)d_in[10];
    const float* b1_2 = (const float*)d_in[11];
    const float* W2_2 = (const float*)d_in[12];
    const float* b2_2 = (const float*)d_in[13];
    float* outp = (float*)d_out;

    // workspace layout (plist first for 8B alignment)
    unsigned long long* plist = (unsigned long long*)d_ws;        // SPLIT*NPTS*6
    float* x0  = (float*)(plist + (size_t)SPLIT * NPTS * KNB);    // 32768 x 64
    float* x1  = x0 + (size_t)NPTS * 64;                          // 32768 x 32
    float* sqb = x1 + (size_t)NPTS * 32;                          // 32768
    float* T0  = sqb + NPTS;                                      // 64 x 64
    float* T1  = T0 + 4096;                                       // 32 x 128
    float* T2  = T1 + 4096;                                       // 64 x 64
    int*   nbr = (int*)(T2 + 4096);                               // 32768 x 6

    const dim3 gscan(NN / 512, NB, SPLIT);   // (4,16,8) x 256 thr
    const int  mgrid = NPTS / 256;
    const int  pgrid = NPTS / 64;

    prep_w<<<16, 256, 0, stream>>>(W1_0, W1_1, W1_2, T0, T1, T2);

    // ---- layer 0: x (32) -> x0 (64), relu ----
    sq_kernel<32><<<NPTS / 256, 256, 0, stream>>>(x, sqb);
    knn_scan<32, 2><<<gscan, 256, 0, stream>>>(x, sqb, plist);
    knn_merge<<<mgrid, 256, 0, stream>>>(plist, nbr);
    mlp_kernel<32, 64, false, 3><<<pgrid, 384, 0, stream>>>(x, nbr, T0, b1_0, W2_0, b2_0, nullptr, x0);

    // ---- layer 1: x0 (64) -> x1 (32), relu ----
    sq_kernel<64><<<NPTS / 256, 256, 0, stream>>>(x0, sqb);
    knn_scan<64, 2><<<gscan, 256, 0, stream>>>(x0, sqb, plist);
    knn_merge<<<mgrid, 256, 0, stream>>>(plist, nbr);
    mlp_kernel<64, 32, false, 2><<<pgrid, 384, 0, stream>>>(x0, nbr, T1, b1_1, W2_1, b2_1, nullptr, x1);

    // ---- layer 2: x1 (32) -> out (64), +x0 residual, relu ----
    sq_kernel<32><<<NPTS / 256, 256, 0, stream>>>(x1, sqb);
    knn_scan<32, 2><<<gscan, 256, 0, stream>>>(x1, sqb, plist);
    knn_merge<<<mgrid, 256, 0, stream>>>(plist, nbr);
    mlp_kernel<32, 64, true, 3><<<pgrid, 384, 0, stream>>>(x1, nbr, T2, b1_2, W2_2, b2_2, x0, outp);
}